// Round 2
// baseline (204.770 us; speedup 1.0000x reference)
//
#include <hip/hip_runtime.h>
#include <hip/hip_bf16.h>

// Chamfer distance, B=4, N=M=8192, D=3, fp32.
// R1: (a) targets read via the SCALAR pipe (block-uniform loads -> s_load into
// SGPRs, VALU does only 3 FMA + 1 min per pair, tn amortized over QPT=4);
// (b) single fused kernel: min + atomicMin(ws) + arrival counter + last-block
// reduction -> out. Graph nodes: 1 memset + 1 kernel (was 2+2).

#define BATCH 4
#define NPTS 8192             // N == M
#define QPT 4                 // queries per thread
#define BLK 256
#define QPB (QPT * BLK)       // 1024 queries per block
#define QCHUNKS (NPTS / QPB)  // 8
#define MC 512                // targets per block chunk
#define TCHUNKS (NPTS / MC)   // 16
#define TOTALQ (BATCH * NPTS) // 32768
#define NBLOCKS (BATCH * QCHUNKS * TCHUNKS * 2) // 1024

__device__ __forceinline__ unsigned int flip_f32(float f) {
    unsigned int u = __float_as_uint(f);
    return (u & 0x80000000u) ? ~u : (u | 0x80000000u); // monotone ascending
}
__device__ __forceinline__ float unflip_f32(unsigned int u) {
    return (u & 0x80000000u) ? __uint_as_float(u ^ 0x80000000u)
                             : __uint_as_float(~u);
}

__global__ __launch_bounds__(BLK) void chamfer_fused_kernel(
        const float* __restrict__ pred, const float* __restrict__ target,
        unsigned int* __restrict__ wsmin, float* __restrict__ out)
{
    const int dir = blockIdx.z;
    const float* __restrict__ Q  = (dir == 0) ? pred : target;
    const float* __restrict__ Tg = (dir == 0) ? target : pred;

    const int b  = blockIdx.x >> 3;       // QCHUNKS == 8
    const int qc = blockIdx.x & 7;

    // ---- load queries (per-lane) ----
    float fx[QPT], fy[QPT], fz[QPT], qn[QPT], mn[QPT];
    int   qidx[QPT];
    #pragma unroll
    for (int k = 0; k < QPT; ++k) {
        int nl = qc * QPB + threadIdx.x + k * BLK;   // [0, NPTS)
        qidx[k] = b * NPTS + nl;                     // [0, TOTALQ)
        const float* qp = Q + (size_t)qidx[k] * 3;
        float x = qp[0], y = qp[1], z = qp[2];
        fx[k] = -2.0f * x; fy[k] = -2.0f * y; fz[k] = -2.0f * z;
        qn[k] = x * x + y * y + z * z;
        mn[k] = 3.4e38f;
    }

    // ---- main loop: targets via uniform (scalar) loads ----
    // 4 targets per group: 12 uniform floats -> SGPRs. Per target:
    // 3 VALU for tn + QPT*(3 fma + 1 min).
    const float* __restrict__ tp =
        Tg + ((size_t)b * NPTS + (size_t)blockIdx.y * MC) * 3;
    for (int g = 0; g < MC / 4; ++g) {
        float s[12];
        #pragma unroll
        for (int i = 0; i < 12; ++i) s[i] = tp[g * 12 + i];
        #pragma unroll
        for (int t = 0; t < 4; ++t) {
            float tx = s[3 * t], ty = s[3 * t + 1], tz = s[3 * t + 2];
            float tn = fmaf(tz, tz, fmaf(ty, ty, tx * tx));
            #pragma unroll
            for (int k = 0; k < QPT; ++k) {
                float d = fmaf(fx[k], tx,
                          fmaf(fy[k], ty,
                          fmaf(fz[k], tz, tn)));
                mn[k] = fminf(mn[k], d);
            }
        }
    }

    // ---- combine across target chunks via device-scope atomicMin ----
    const unsigned int base = (dir == 0) ? 0u : (unsigned int)TOTALQ;
    #pragma unroll
    for (int k = 0; k < QPT; ++k) {
        float total = mn[k] + qn[k];
        atomicMin(&wsmin[base + (unsigned int)qidx[k]], flip_f32(total));
    }

    // ---- arrival counter; last block reduces ----
    __shared__ int lastFlag;
    __shared__ float wsum[BLK / 64];
    __syncthreads();                       // all atomicMins of this block issued
    if (threadIdx.x == 0) {
        __threadfence();                   // release: minima visible device-wide
        unsigned int old = atomicAdd(&wsmin[2 * TOTALQ], 1u); // init 0xFFFFFFFF
        lastFlag = (old == (unsigned int)(NBLOCKS - 2)) ? 1 : 0;
    }
    __syncthreads();
    if (!lastFlag) return;

    __threadfence();                       // acquire
    float acc = 0.0f;
    for (int i = threadIdx.x; i < 2 * TOTALQ; i += BLK) {
        unsigned int u = __hip_atomic_load(&wsmin[i], __ATOMIC_RELAXED,
                                           __HIP_MEMORY_SCOPE_AGENT);
        acc += unflip_f32(u);
    }
    #pragma unroll
    for (int off = 32; off > 0; off >>= 1)
        acc += __shfl_down(acc, off, 64);
    int lane = threadIdx.x & 63, wid = threadIdx.x >> 6;
    if (lane == 0) wsum[wid] = acc;
    __syncthreads();
    if (threadIdx.x == 0) {
        float ssum = 0.0f;
        #pragma unroll
        for (int w = 0; w < BLK / 64; ++w) ssum += wsum[w];
        out[0] = ssum * (1.0f / (float)TOTALQ);
    }
}

extern "C" void kernel_launch(void* const* d_in, const int* in_sizes, int n_in,
                              void* d_out, int out_size, void* d_ws, size_t ws_size,
                              hipStream_t stream) {
    const float* pred   = (const float*)d_in[0];
    const float* target = (const float*)d_in[1];
    float*       out    = (float*)d_out;
    unsigned int* wsmin = (unsigned int*)d_ws;

    // minima -> 0xFFFFFFFF (=+inf in flipped encoding); counter -> 0xFFFFFFFF (=-1)
    hipMemsetAsync(wsmin, 0xFF, (size_t)(2 * TOTALQ + 1) * sizeof(unsigned int),
                   stream);

    dim3 grid(BATCH * QCHUNKS, TCHUNKS, 2);   // 32 x 16 x 2 = 1024 blocks
    dim3 block(BLK);
    hipLaunchKernelGGL(chamfer_fused_kernel, grid, block, 0, stream,
                       pred, target, wsmin, out);
}

// Round 3
// 166.354 us; speedup vs baseline: 1.2309x; 1.2309x over previous
//
#include <hip/hip_runtime.h>
#include <hip/hip_bf16.h>

// Chamfer distance, B=4, N=M=8192, D=3, fp32.
// R2: revert to LDS-broadcast tiles (R0 structure, proven VALU-bound), but:
//  - QPT=8 queries/thread -> halves ds_read_b128 traffic per FMA (R0 was
//    LDS-pipe-bound: 128 B/cyc demand vs ~85 B/cyc capability)
//  - process targets in PAIRS with min3 folding: mn = min(min(mn,d0),d1)
//    -> v_min3_f32, 7 VALU per 2 pairs (3.5 ops/pair vs 4)
//  - keep single fused kernel (atomicMin ws + arrival counter + last-block
//    reduction), 1 memset + 1 kernel graph nodes.

#define BATCH 4
#define NPTS 8192             // N == M
#define QPT 8                 // queries per thread
#define BLK 256
#define QPB (QPT * BLK)       // 2048 queries per block
#define QCHUNKS (NPTS / QPB)  // 4
#define MC 512                // targets staged per block
#define TCHUNKS (NPTS / MC)   // 16
#define TOTALQ (BATCH * NPTS) // 32768
#define NBLOCKS (BATCH * QCHUNKS * TCHUNKS * 2) // 512

__device__ __forceinline__ unsigned int flip_f32(float f) {
    unsigned int u = __float_as_uint(f);
    return (u & 0x80000000u) ? ~u : (u | 0x80000000u); // monotone ascending
}
__device__ __forceinline__ float unflip_f32(unsigned int u) {
    return (u & 0x80000000u) ? __uint_as_float(u ^ 0x80000000u)
                             : __uint_as_float(~u);
}

__global__ __launch_bounds__(BLK) void chamfer_fused_kernel(
        const float* __restrict__ pred, const float* __restrict__ target,
        unsigned int* __restrict__ wsmin, float* __restrict__ out)
{
    const int dir = blockIdx.z;
    const float* __restrict__ Q  = (dir == 0) ? pred : target;
    const float* __restrict__ Tg = (dir == 0) ? target : pred;

    const int b  = blockIdx.x >> 2;       // QCHUNKS == 4
    const int qc = blockIdx.x & 3;

    __shared__ float4 tile[MC];           // 8 KB

    // ---- stage targets: (tx, ty, tz, tn) ----
    const int tbase = blockIdx.y * MC;
    #pragma unroll
    for (int kk = 0; kk < MC / BLK; ++kk) {
        int j = threadIdx.x + kk * BLK;
        const float* tp = Tg + ((size_t)b * NPTS + tbase + j) * 3;
        float tx = tp[0], ty = tp[1], tz = tp[2];
        tile[j] = make_float4(tx, ty, tz,
                              fmaf(tz, tz, fmaf(ty, ty, tx * tx)));
    }

    // ---- load queries (per-lane) ----
    float fx[QPT], fy[QPT], fz[QPT], qn[QPT], mn[QPT];
    int   qidx[QPT];
    #pragma unroll
    for (int k = 0; k < QPT; ++k) {
        int nl = qc * QPB + threadIdx.x + k * BLK;   // [0, NPTS)
        qidx[k] = b * NPTS + nl;                     // [0, TOTALQ)
        const float* qp = Q + (size_t)qidx[k] * 3;
        float x = qp[0], y = qp[1], z = qp[2];
        fx[k] = -2.0f * x; fy[k] = -2.0f * y; fz[k] = -2.0f * z;
        qn[k] = fmaf(z, z, fmaf(y, y, x * x));
        mn[k] = 3.4e38f;
    }
    __syncthreads();

    // ---- main loop: target pairs, 3+3 FMA + 1 min3 per query ----
    #pragma unroll 2
    for (int j = 0; j < MC; j += 2) {
        float4 t0 = tile[j];
        float4 t1 = tile[j + 1];
        #pragma unroll
        for (int k = 0; k < QPT; ++k) {
            float d0 = fmaf(fx[k], t0.x,
                       fmaf(fy[k], t0.y,
                       fmaf(fz[k], t0.z, t0.w)));
            float d1 = fmaf(fx[k], t1.x,
                       fmaf(fy[k], t1.y,
                       fmaf(fz[k], t1.z, t1.w)));
            mn[k] = fminf(fminf(mn[k], d0), d1);   // -> v_min3_f32
        }
    }

    // ---- combine across target chunks via device-scope atomicMin ----
    const unsigned int base = (dir == 0) ? 0u : (unsigned int)TOTALQ;
    #pragma unroll
    for (int k = 0; k < QPT; ++k) {
        float total = mn[k] + qn[k];
        atomicMin(&wsmin[base + (unsigned int)qidx[k]], flip_f32(total));
    }

    // ---- arrival counter; last block reduces ----
    __shared__ int lastFlag;
    __shared__ float wsum[BLK / 64];
    __syncthreads();                       // all atomicMins of this block issued
    if (threadIdx.x == 0) {
        __threadfence();                   // release: minima visible device-wide
        unsigned int old = atomicAdd(&wsmin[2 * TOTALQ], 1u); // init 0xFFFFFFFF
        lastFlag = (old == (unsigned int)(NBLOCKS - 2)) ? 1 : 0;
    }
    __syncthreads();
    if (!lastFlag) return;

    __threadfence();                       // acquire
    float acc = 0.0f;
    for (int i = threadIdx.x; i < 2 * TOTALQ; i += BLK) {
        unsigned int u = __hip_atomic_load(&wsmin[i], __ATOMIC_RELAXED,
                                           __HIP_MEMORY_SCOPE_AGENT);
        acc += unflip_f32(u);
    }
    #pragma unroll
    for (int off = 32; off > 0; off >>= 1)
        acc += __shfl_down(acc, off, 64);
    int lane = threadIdx.x & 63, wid = threadIdx.x >> 6;
    if (lane == 0) wsum[wid] = acc;
    __syncthreads();
    if (threadIdx.x == 0) {
        float ssum = 0.0f;
        #pragma unroll
        for (int w = 0; w < BLK / 64; ++w) ssum += wsum[w];
        out[0] = ssum * (1.0f / (float)TOTALQ);
    }
}

extern "C" void kernel_launch(void* const* d_in, const int* in_sizes, int n_in,
                              void* d_out, int out_size, void* d_ws, size_t ws_size,
                              hipStream_t stream) {
    const float* pred   = (const float*)d_in[0];
    const float* target = (const float*)d_in[1];
    float*       out    = (float*)d_out;
    unsigned int* wsmin = (unsigned int*)d_ws;

    // minima -> 0xFFFFFFFF (=+inf in flipped encoding); counter -> 0xFFFFFFFF (=-1)
    hipMemsetAsync(wsmin, 0xFF, (size_t)(2 * TOTALQ + 1) * sizeof(unsigned int),
                   stream);

    dim3 grid(BATCH * QCHUNKS, TCHUNKS, 2);   // 16 x 16 x 2 = 512 blocks
    dim3 block(BLK);
    hipLaunchKernelGGL(chamfer_fused_kernel, grid, block, 0, stream,
                       pred, target, wsmin, out);
}

// Round 4
// 102.190 us; speedup vs baseline: 2.0038x; 1.6279x over previous
//
#include <hip/hip_runtime.h>
#include <hip/hip_bf16.h>

// Chamfer distance, B=4, N=M=8192, D=3, fp32.
// R3: latency-bound diagnosis from R2 (VALUBusy 40%, Occ 8%). Fixes:
//  - 1024 blocks (TCHUNKS=32, MC=256) -> 16 waves/CU for latency hiding
//  - explicit register prefetch of next target pair (loads hoisted one full
//    compute body ahead of use; unroll 2 keeps two batches in flight)
//  - separate parallel-ish reduce kernel (1 block x 1024 thr, uint4 loads);
//    no arrival counter, no single-block tail inside the big kernel
// Math unchanged: min_m ||q-t||^2 = qn + min_m(tn - 2<q,t>); 3 FMA per pair,
// min3 folding over target pairs -> 3.5 VALU lane-ops/pair (floor 23.9 us).

#define BATCH 4
#define NPTS 8192             // N == M
#define QPT 8                 // queries per thread
#define BLK 256
#define QPB (QPT * BLK)       // 2048 queries per block
#define QCHUNKS (NPTS / QPB)  // 4
#define MC 256                // targets staged per block
#define TCHUNKS (NPTS / MC)   // 32
#define TOTALQ (BATCH * NPTS) // 32768

__device__ __forceinline__ unsigned int flip_f32(float f) {
    unsigned int u = __float_as_uint(f);
    return (u & 0x80000000u) ? ~u : (u | 0x80000000u); // monotone ascending
}
__device__ __forceinline__ float unflip_f32(unsigned int u) {
    return (u & 0x80000000u) ? __uint_as_float(u ^ 0x80000000u)
                             : __uint_as_float(~u);
}

__global__ __launch_bounds__(BLK) void chamfer_min_kernel(
        const float* __restrict__ pred, const float* __restrict__ target,
        unsigned int* __restrict__ wsmin)
{
    const int dir = blockIdx.z;
    const float* __restrict__ Q  = (dir == 0) ? pred : target;
    const float* __restrict__ Tg = (dir == 0) ? target : pred;

    const int b  = blockIdx.x >> 2;       // QCHUNKS == 4
    const int qc = blockIdx.x & 3;

    __shared__ float4 tile[MC + 2];       // +2: prefetch overrun slots

    // ---- stage targets: (tx, ty, tz, tn), one per thread ----
    {
        int j = threadIdx.x;              // MC == BLK
        const float* tp = Tg + ((size_t)b * NPTS + (size_t)blockIdx.y * MC + j) * 3;
        float tx = tp[0], ty = tp[1], tz = tp[2];
        tile[j] = make_float4(tx, ty, tz,
                              fmaf(tz, tz, fmaf(ty, ty, tx * tx)));
    }

    // ---- load queries (per-lane) ----
    float fx[QPT], fy[QPT], fz[QPT], qn[QPT], mn[QPT];
    int   qidx[QPT];
    #pragma unroll
    for (int k = 0; k < QPT; ++k) {
        int nl = qc * QPB + threadIdx.x + k * BLK;   // [0, NPTS)
        qidx[k] = b * NPTS + nl;                     // [0, TOTALQ)
        const float* qp = Q + (size_t)qidx[k] * 3;
        float x = qp[0], y = qp[1], z = qp[2];
        fx[k] = -2.0f * x; fy[k] = -2.0f * y; fz[k] = -2.0f * z;
        qn[k] = fmaf(z, z, fmaf(y, y, x * x));
        mn[k] = 3.4e38f;
    }
    __syncthreads();

    // ---- main loop: software-pipelined target pairs ----
    float4 t0 = tile[0], t1 = tile[1];
    #pragma unroll 2
    for (int j = 0; j < MC; j += 2) {
        float4 n0 = tile[j + 2];          // prefetch next pair (overruns into
        float4 n1 = tile[j + 3];          //  tile[MC..MC+1] on last iter: unused)
        #pragma unroll
        for (int k = 0; k < QPT; ++k) {
            float d0 = fmaf(fx[k], t0.x,
                       fmaf(fy[k], t0.y,
                       fmaf(fz[k], t0.z, t0.w)));
            float d1 = fmaf(fx[k], t1.x,
                       fmaf(fy[k], t1.y,
                       fmaf(fz[k], t1.z, t1.w)));
            mn[k] = fminf(fminf(mn[k], d0), d1);   // -> v_min3_f32
        }
        t0 = n0; t1 = n1;
    }

    // ---- combine across target chunks via device-scope atomicMin ----
    const unsigned int base = (dir == 0) ? 0u : (unsigned int)TOTALQ;
    #pragma unroll
    for (int k = 0; k < QPT; ++k) {
        float total = mn[k] + qn[k];
        atomicMin(&wsmin[base + (unsigned int)qidx[k]], flip_f32(total));
    }
}

__global__ __launch_bounds__(1024) void chamfer_reduce_kernel(
        const uint4* __restrict__ wsmin, float* __restrict__ out)
{
    float acc = 0.0f;
    #pragma unroll
    for (int i = threadIdx.x; i < (2 * TOTALQ) / 4; i += 1024) {  // 16 iters
        uint4 u = wsmin[i];
        acc += (unflip_f32(u.x) + unflip_f32(u.y)) +
               (unflip_f32(u.z) + unflip_f32(u.w));
    }
    #pragma unroll
    for (int off = 32; off > 0; off >>= 1)
        acc += __shfl_down(acc, off, 64);
    __shared__ float wsum[16];
    int lane = threadIdx.x & 63, wid = threadIdx.x >> 6;
    if (lane == 0) wsum[wid] = acc;
    __syncthreads();
    if (threadIdx.x == 0) {
        float ssum = 0.0f;
        #pragma unroll
        for (int w = 0; w < 16; ++w) ssum += wsum[w];
        out[0] = ssum * (1.0f / (float)TOTALQ);
    }
}

extern "C" void kernel_launch(void* const* d_in, const int* in_sizes, int n_in,
                              void* d_out, int out_size, void* d_ws, size_t ws_size,
                              hipStream_t stream) {
    const float* pred   = (const float*)d_in[0];
    const float* target = (const float*)d_in[1];
    float*       out    = (float*)d_out;
    unsigned int* wsmin = (unsigned int*)d_ws;

    // minima -> 0xFFFFFFFF (= +inf in flipped encoding)
    hipMemsetAsync(wsmin, 0xFF, (size_t)(2 * TOTALQ) * sizeof(unsigned int),
                   stream);

    dim3 grid(BATCH * QCHUNKS, TCHUNKS, 2);   // 16 x 32 x 2 = 1024 blocks
    hipLaunchKernelGGL(chamfer_min_kernel, grid, dim3(BLK), 0, stream,
                       pred, target, wsmin);
    hipLaunchKernelGGL(chamfer_reduce_kernel, dim3(1), dim3(1024), 0, stream,
                       (const uint4*)wsmin, out);
}

// Round 5
// 101.480 us; speedup vs baseline: 2.0178x; 1.0070x over previous
//
#include <hip/hip_runtime.h>
#include <hip/hip_bf16.h>

// Chamfer distance, B=4, N=M=8192, D=3, fp32.
// R4: R3's WRITE_SIZE showed all 2.1M atomicMins hit HBM (atomic tail tax).
// Replace cross-chunk atomic combine with plain coalesced stores of per-chunk
// partial minima (each ws slot written by exactly one thread -> no memset, no
// flipped-uint encoding), then a 256-block reduce kernel (min over TCHUNKS,
// block-sum, one atomicAdd per block). out[0] zeroed by the min kernel.
// Graph: 2 kernel nodes, 0 memsets, 0 HBM atomics in the hot path.

#define BATCH 4
#define NPTS 8192             // N == M
#define QPT 8                 // queries per thread
#define BLK 256
#define QPB (QPT * BLK)       // 2048 queries per block
#define QCHUNKS (NPTS / QPB)  // 4
#define MC 256                // targets staged per block
#define TCHUNKS (NPTS / MC)   // 32
#define TOTALQ (BATCH * NPTS) // 32768

__global__ __launch_bounds__(BLK) void chamfer_min_kernel(
        const float* __restrict__ pred, const float* __restrict__ target,
        float* __restrict__ wspart, float* __restrict__ out)
{
    const int dir = blockIdx.z;
    const float* __restrict__ Q  = (dir == 0) ? pred : target;
    const float* __restrict__ Tg = (dir == 0) ? target : pred;

    const int b  = blockIdx.x >> 2;       // QCHUNKS == 4
    const int qc = blockIdx.x & 3;

    // zero the output accumulator once per launch (reduce runs after kernel
    // boundary, so ordering is safe on every graph replay)
    if (blockIdx.x == 0 && blockIdx.y == 0 && blockIdx.z == 0 &&
        threadIdx.x == 0) {
        out[0] = 0.0f;
    }

    __shared__ float4 tile[MC + 2];       // +2: prefetch overrun slots

    // ---- stage targets: (tx, ty, tz, tn), one per thread (MC == BLK) ----
    {
        int j = threadIdx.x;
        const float* tp = Tg + ((size_t)b * NPTS + (size_t)blockIdx.y * MC + j) * 3;
        float tx = tp[0], ty = tp[1], tz = tp[2];
        tile[j] = make_float4(tx, ty, tz,
                              fmaf(tz, tz, fmaf(ty, ty, tx * tx)));
    }

    // ---- load queries (per-lane) ----
    float fx[QPT], fy[QPT], fz[QPT], qn[QPT], mn[QPT];
    int   nl[QPT];
    #pragma unroll
    for (int k = 0; k < QPT; ++k) {
        nl[k] = qc * QPB + threadIdx.x + k * BLK;    // [0, NPTS)
        const float* qp = Q + ((size_t)b * NPTS + nl[k]) * 3;
        float x = qp[0], y = qp[1], z = qp[2];
        fx[k] = -2.0f * x; fy[k] = -2.0f * y; fz[k] = -2.0f * z;
        qn[k] = fmaf(z, z, fmaf(y, y, x * x));
        mn[k] = 3.4e38f;
    }
    __syncthreads();

    // ---- main loop: software-pipelined target pairs ----
    float4 t0 = tile[0], t1 = tile[1];
    #pragma unroll 2
    for (int j = 0; j < MC; j += 2) {
        float4 n0 = tile[j + 2];          // prefetch next pair (last-iter
        float4 n1 = tile[j + 3];          //  overrun lands in pad slots)
        #pragma unroll
        for (int k = 0; k < QPT; ++k) {
            float d0 = fmaf(fx[k], t0.x,
                       fmaf(fy[k], t0.y,
                       fmaf(fz[k], t0.z, t0.w)));
            float d1 = fmaf(fx[k], t1.x,
                       fmaf(fy[k], t1.y,
                       fmaf(fz[k], t1.z, t1.w)));
            mn[k] = fminf(fminf(mn[k], d0), d1);   // -> v_min3_f32
        }
        t0 = n0; t1 = n1;
    }

    // ---- plain coalesced store of this block's partial minima ----
    // layout: wspart[(dir*TCHUNKS + tc) * TOTALQ + b*NPTS + nl]
    float* wp = wspart + ((size_t)(dir * TCHUNKS + blockIdx.y) * TOTALQ
                          + (size_t)b * NPTS);
    #pragma unroll
    for (int k = 0; k < QPT; ++k) {
        wp[nl[k]] = mn[k] + qn[k];
    }
}

__global__ __launch_bounds__(BLK) void chamfer_reduce_kernel(
        const float* __restrict__ wspart, float* __restrict__ out)
{
    // one (dir, q) pair per thread; 65536 threads = 256 blocks x 256
    const int g   = blockIdx.x * BLK + threadIdx.x;
    const int dir = g >> 15;
    const int q   = g & (TOTALQ - 1);

    const float* wp = wspart + (size_t)(dir * TCHUNKS) * TOTALQ + q;
    float m = wp[0];
    #pragma unroll
    for (int tc = 1; tc < TCHUNKS; ++tc)
        m = fminf(m, wp[(size_t)tc * TOTALQ]);

    float acc = m * (1.0f / (float)TOTALQ);
    #pragma unroll
    for (int off = 32; off > 0; off >>= 1)
        acc += __shfl_down(acc, off, 64);
    __shared__ float wsum[BLK / 64];
    int lane = threadIdx.x & 63, wid = threadIdx.x >> 6;
    if (lane == 0) wsum[wid] = acc;
    __syncthreads();
    if (threadIdx.x == 0) {
        float ssum = 0.0f;
        #pragma unroll
        for (int w = 0; w < BLK / 64; ++w) ssum += wsum[w];
        atomicAdd(out, ssum);
    }
}

extern "C" void kernel_launch(void* const* d_in, const int* in_sizes, int n_in,
                              void* d_out, int out_size, void* d_ws, size_t ws_size,
                              hipStream_t stream) {
    const float* pred   = (const float*)d_in[0];
    const float* target = (const float*)d_in[1];
    float*       out    = (float*)d_out;
    float*       wspart = (float*)d_ws;   // 2*TCHUNKS*TOTALQ floats = 8 MB

    dim3 grid(BATCH * QCHUNKS, TCHUNKS, 2);   // 16 x 32 x 2 = 1024 blocks
    hipLaunchKernelGGL(chamfer_min_kernel, grid, dim3(BLK), 0, stream,
                       pred, target, wspart, out);
    hipLaunchKernelGGL(chamfer_reduce_kernel, dim3(2 * TOTALQ / BLK), dim3(BLK),
                       0, stream, wspart, out);
}